// Round 1
// baseline (3919.886 us; speedup 1.0000x reference)
//
#include <hip/hip_runtime.h>

// Problem constants (B=8, S=2048, D=1024, H=4096, E=8, CAP_FACTOR=1.5)
#define NTOK 16384
#define DDIM 1024
#define EEXP 8
#define HDIM 4096
#define CAP  3072               // int(1.5 * 16384 / 8)
#define ECAP (EEXP*CAP)         // 24576

// Workspace layout (bytes)
#define OFF_GATE 0                          // float[NTOK]
#define OFF_GIDX (NTOK*4)                   // int[NTOK]
#define OFF_SLOT (2*NTOK*4)                 // int[NTOK]  (slot or -1)
#define OFF_TOS  (3*NTOK*4)                 // int[ECAP]  (token of slot)
#define OFF_CNT  (OFF_TOS + ECAP*4)         // int[8]     (kept count per expert)
#define OFF_PIMP (OFF_CNT + 64)             // float[4096*8] per-block importance partials
#define OFF_H    (1<<19)                    // h buffer

__device__ __forceinline__ float siluf(float v){ return v/(1.0f+__expf(-v)); }

// ---------------------------------------------------------------------------
// Router: one wave per token. logits = x@Wr + br, softmax, gate/argmax,
// per-block importance partial sums.
// ---------------------------------------------------------------------------
__global__ __launch_bounds__(256) void router_kernel(
    const float* __restrict__ x, const float* __restrict__ Wr,
    const float* __restrict__ br, float* __restrict__ gate_value,
    int* __restrict__ gate_idx, float* __restrict__ partial_imp)
{
  __shared__ float pbuf[4][8];
  const int wave = threadIdx.x >> 6;
  const int lane = threadIdx.x & 63;
  const int n = blockIdx.x*4 + wave;
  float acc[8];
#pragma unroll
  for (int e=0;e<8;e++) acc[e]=0.0f;
  const float* xr = x + (size_t)n*DDIM;
#pragma unroll
  for (int k=0;k<16;k++){
    const int d = k*64 + lane;
    const float xv = xr[d];
    const float4 w0 = ((const float4*)(Wr + (size_t)d*8))[0];
    const float4 w1 = ((const float4*)(Wr + (size_t)d*8))[1];
    acc[0] += xv*w0.x; acc[1] += xv*w0.y; acc[2] += xv*w0.z; acc[3] += xv*w0.w;
    acc[4] += xv*w1.x; acc[5] += xv*w1.y; acc[6] += xv*w1.z; acc[7] += xv*w1.w;
  }
#pragma unroll
  for (int e=0;e<8;e++){
    acc[e] += __shfl_xor(acc[e], 32, 64);
    acc[e] += __shfl_xor(acc[e], 16, 64);
    acc[e] += __shfl_xor(acc[e],  8, 64);
    acc[e] += __shfl_xor(acc[e],  4, 64);
    acc[e] += __shfl_xor(acc[e],  2, 64);
    acc[e] += __shfl_xor(acc[e],  1, 64);
  }
  if (lane==0){
    float lg[8];
    float mx = -3.4e38f;
    int bi = 0;
#pragma unroll
    for (int e=0;e<8;e++) lg[e] = acc[e] + br[e];
#pragma unroll
    for (int e=0;e<8;e++){ if (lg[e] > mx){ mx = lg[e]; bi = e; } }  // first-max, matches argmax
    float s = 0.f;
#pragma unroll
    for (int e=0;e<8;e++){ lg[e] = __expf(lg[e]-mx); s += lg[e]; }
    const float inv = 1.0f/s;      // max prob = exp(0)/s
    gate_value[n] = inv;
    gate_idx[n] = bi;
#pragma unroll
    for (int e=0;e<8;e++) pbuf[wave][e] = lg[e]*inv;
  }
  __syncthreads();
  if (threadIdx.x < 8){
    partial_imp[(size_t)blockIdx.x*8 + threadIdx.x] =
      pbuf[0][threadIdx.x]+pbuf[1][threadIdx.x]+pbuf[2][threadIdx.x]+pbuf[3][threadIdx.x];
  }
}

// ---------------------------------------------------------------------------
// Scan: FIFO positions per expert (single block), capacity drop, slot scatter,
// importance reduction + both aux losses.
// ---------------------------------------------------------------------------
__global__ __launch_bounds__(256) void scan_kernel(
    const int* __restrict__ gate_idx, const float* __restrict__ partial_imp,
    int* __restrict__ slot_or_neg, int* __restrict__ tok_of_slot,
    int* __restrict__ cnt, float* __restrict__ out_losses)
{
  __shared__ int hist[256][8];
  __shared__ float impbuf[32][8];
  const int t = threadIdx.x;
  int h[8];
#pragma unroll
  for (int e=0;e<8;e++) h[e]=0;
  const int base = t*64;
  for (int i=0;i<64;i++) h[gate_idx[base+i]]++;
#pragma unroll
  for (int e=0;e<8;e++) hist[t][e]=h[e];
  {
    const int e = t & 7, c = t >> 3;   // 32 chunks x 8 experts
    float s = 0.f;
    for (int r=c; r<4096; r+=32) s += partial_imp[(size_t)r*8+e];
    impbuf[c][e] = s;
  }
  __syncthreads();
  if (t < 8){
    int run = 0;
    for (int i=0;i<256;i++){ int v = hist[i][t]; hist[i][t] = run; run += v; }
    cnt[t] = run < CAP ? run : CAP;
  }
  __syncthreads();
#pragma unroll
  for (int e=0;e<8;e++) h[e]=hist[t][e];
  for (int i=0;i<64;i++){
    const int n = base+i;
    const int e = gate_idx[n];
    const int p = h[e]++;
    if (p < CAP){ const int s = e*CAP+p; slot_or_neg[n]=s; tok_of_slot[s]=n; }
    else slot_or_neg[n] = -1;
  }
  if (t==0){
    float imp[8]; float m = 0.f;
    for (int e=0;e<8;e++){ float s=0.f; for (int c=0;c<32;c++) s+=impbuf[c][e]; imp[e]=s; m+=s; }
    m *= 0.125f;
    float var = 0.f;
    for (int e=0;e<8;e++){ const float d=imp[e]-m; var += d*d; }
    var *= 0.125f;
    out_losses[0] = 1.0f;           // l1: mean of softmax row-sums == 1
    out_losses[1] = var/(m*m);      // (std/mean)^2, population std
  }
}

// ---------------------------------------------------------------------------
// Grouped FFN GEMM. PHASE 1: h = silu(X_gathered @ W1[e] + b1[e])
//                  PHASE 2: out[tok] = (h @ W2[e] + b2[e]) * gate[tok]
// 128x128x16 tile, 256 threads, 8x8 micro (split 4+4 fragments).
// Expert slots are a contiguous prefix -> tiles beyond cnt[e] early-exit.
// ---------------------------------------------------------------------------
template<int PHASE>
__global__ __launch_bounds__(256) void ffn_gemm(
    const float* __restrict__ A, const float* __restrict__ W,
    const float* __restrict__ bias, const int* __restrict__ tok_of_slot,
    const int* __restrict__ cnt, const float* __restrict__ gate_value,
    float* __restrict__ Out, int rt_base, int h_base_row)
{
  constexpr int K  = (PHASE==1)? DDIM : HDIM;
  constexpr int NN = (PHASE==1)? HDIM : DDIM;
  const int rowtile = rt_base + blockIdx.y;
  const int coltile = blockIdx.x;
  const int e  = rowtile / (CAP/128);       // 24 row-tiles per expert
  const int r0 = rowtile*128 - e*CAP;
  const int ce = cnt[e];
  if (r0 >= ce) return;                      // fully-empty tile

  __shared__ float As[16][132];              // A^T: As[k][m], +4 pad
  __shared__ float Bs[16][132];              // Bs[k][n]

  const int arow = threadIdx.x >> 2;         // 0..63 (two rows per thread)
  const int akq  = (threadIdx.x & 3)*4;      // k sub-offset
  const float* aptr0; const float* aptr1;
  if (PHASE==1){
    const int lr0 = r0 + arow, lr1 = lr0 + 64;
    const int t0 = (lr0 < ce)? tok_of_slot[rowtile*128 + arow]      : 0;
    const int t1 = (lr1 < ce)? tok_of_slot[rowtile*128 + arow + 64] : 0;
    aptr0 = A + (size_t)t0*K + akq;
    aptr1 = A + (size_t)t1*K + akq;
  } else {
    aptr0 = A + (size_t)(rowtile*128 + arow      - h_base_row)*K + akq;
    aptr1 = A + (size_t)(rowtile*128 + arow + 64 - h_base_row)*K + akq;
  }
  const int brow = threadIdx.x >> 5;         // 0..7 (two k-rows per thread)
  const int bcol = (threadIdx.x & 31)*4;
  const float* bptr = W + (size_t)e*K*NN + (size_t)brow*NN + coltile*128 + bcol;

  const int tx = threadIdx.x & 15;
  const int ty = threadIdx.x >> 4;

  float acc[8][8];
#pragma unroll
  for (int i=0;i<8;i++)
#pragma unroll
    for (int j=0;j<8;j++) acc[i][j]=0.0f;

  for (int k0=0; k0<K; k0+=16){
    // prefetch global into regs before barrier (hides latency behind prev compute)
    const float4 a0 = *(const float4*)(aptr0 + k0);
    const float4 a1 = *(const float4*)(aptr1 + k0);
    const float4 b0 = *(const float4*)(bptr + (size_t)k0*NN);
    const float4 b1 = *(const float4*)(bptr + (size_t)(k0+8)*NN);
    __syncthreads();
    As[akq+0][arow] = a0.x; As[akq+1][arow] = a0.y;
    As[akq+2][arow] = a0.z; As[akq+3][arow] = a0.w;
    As[akq+0][arow+64] = a1.x; As[akq+1][arow+64] = a1.y;
    As[akq+2][arow+64] = a1.z; As[akq+3][arow+64] = a1.w;
    *(float4*)&Bs[brow][bcol]   = b0;
    *(float4*)&Bs[brow+8][bcol] = b1;
    __syncthreads();
#pragma unroll
    for (int k=0;k<16;k++){
      const float4 af0 = *(const float4*)&As[k][ty*4];
      const float4 af1 = *(const float4*)&As[k][64+ty*4];
      const float4 bf0 = *(const float4*)&Bs[k][tx*4];
      const float4 bf1 = *(const float4*)&Bs[k][64+tx*4];
      const float a8[8] = {af0.x,af0.y,af0.z,af0.w,af1.x,af1.y,af1.z,af1.w};
      const float b8[8] = {bf0.x,bf0.y,bf0.z,bf0.w,bf1.x,bf1.y,bf1.z,bf1.w};
#pragma unroll
      for (int i=0;i<8;i++)
#pragma unroll
        for (int j=0;j<8;j++) acc[i][j] += a8[i]*b8[j];
    }
  }

  const int colbase = coltile*128;
  const float4 bb0 = *(const float4*)(bias + (size_t)e*NN + colbase + tx*4);
  const float4 bb1 = *(const float4*)(bias + (size_t)e*NN + colbase + 64 + tx*4);

  if (PHASE==1){
#pragma unroll
    for (int i=0;i<8;i++){
      const int lrow = (i<4)? (ty*4+i) : (64+ty*4+i-4);
      float* hr = Out + (size_t)(rowtile*128 + lrow - h_base_row)*NN + colbase;
      float4 v0, v1;
      v0.x = siluf(acc[i][0]+bb0.x); v0.y = siluf(acc[i][1]+bb0.y);
      v0.z = siluf(acc[i][2]+bb0.z); v0.w = siluf(acc[i][3]+bb0.w);
      v1.x = siluf(acc[i][4]+bb1.x); v1.y = siluf(acc[i][5]+bb1.y);
      v1.z = siluf(acc[i][6]+bb1.z); v1.w = siluf(acc[i][7]+bb1.w);
      *(float4*)(hr + tx*4) = v0;
      *(float4*)(hr + 64 + tx*4) = v1;
    }
  } else {
#pragma unroll
    for (int i=0;i<8;i++){
      const int lrow = (i<4)? (ty*4+i) : (64+ty*4+i-4);
      if (r0 + lrow < ce){
        const int tok = tok_of_slot[rowtile*128 + lrow];
        const float g = gate_value[tok];
        float* orow = Out + (size_t)tok*NN + colbase;
        float4 v0, v1;
        v0.x = (acc[i][0]+bb0.x)*g; v0.y = (acc[i][1]+bb0.y)*g;
        v0.z = (acc[i][2]+bb0.z)*g; v0.w = (acc[i][3]+bb0.w)*g;
        v1.x = (acc[i][4]+bb1.x)*g; v1.y = (acc[i][5]+bb1.y)*g;
        v1.z = (acc[i][6]+bb1.z)*g; v1.w = (acc[i][7]+bb1.w)*g;
        *(float4*)(orow + tx*4) = v0;
        *(float4*)(orow + 64 + tx*4) = v1;
      }
    }
  }
}

// ---------------------------------------------------------------------------
// Dropped tokens pass through: out[n] = x[n] * gate[n]
// ---------------------------------------------------------------------------
__global__ __launch_bounds__(256) void passthrough_kernel(
    const float* __restrict__ x, const int* __restrict__ slot_or_neg,
    const float* __restrict__ gate_value, float* __restrict__ out)
{
  const int n = blockIdx.x;
  if (slot_or_neg[n] >= 0) return;
  const float g = gate_value[n];
  float4 v = *(const float4*)(x + (size_t)n*DDIM + threadIdx.x*4);
  v.x*=g; v.y*=g; v.z*=g; v.w*=g;
  *(float4*)(out + (size_t)n*DDIM + threadIdx.x*4) = v;
}

extern "C" void kernel_launch(void* const* d_in, const int* in_sizes, int n_in,
                              void* d_out, int out_size, void* d_ws, size_t ws_size,
                              hipStream_t stream)
{
  const float* x  = (const float*)d_in[0];
  const float* Wr = (const float*)d_in[1];
  const float* br = (const float*)d_in[2];
  const float* W1 = (const float*)d_in[3];
  const float* b1 = (const float*)d_in[4];
  const float* W2 = (const float*)d_in[5];
  const float* b2 = (const float*)d_in[6];
  float* out = (float*)d_out;

  char* ws = (char*)d_ws;
  float* gate_value  = (float*)(ws + OFF_GATE);
  int*   gate_idx    = (int*)  (ws + OFF_GIDX);
  int*   slot_or_neg = (int*)  (ws + OFF_SLOT);
  int*   tok_of_slot = (int*)  (ws + OFF_TOS);
  int*   cnt         = (int*)  (ws + OFF_CNT);
  float* partial_imp = (float*)(ws + OFF_PIMP);
  float* hbuf        = (float*)(ws + OFF_H);

  router_kernel<<<NTOK/4, 256, 0, stream>>>(x, Wr, br, gate_value, gate_idx, partial_imp);
  scan_kernel<<<1, 256, 0, stream>>>(gate_idx, partial_imp, slot_or_neg, tok_of_slot,
                                     cnt, out + (size_t)NTOK*DDIM);

  const size_t need_full = (size_t)OFF_H + (size_t)ECAP*HDIM*4;
  if (ws_size >= need_full){
    // single grouped launch over all experts; h holds all E*C rows
    ffn_gemm<1><<<dim3(HDIM/128, ECAP/128), 256, 0, stream>>>(
        x, W1, b1, tok_of_slot, cnt, gate_value, hbuf, 0, 0);
    ffn_gemm<2><<<dim3(DDIM/128, ECAP/128), 256, 0, stream>>>(
        hbuf, W2, b2, tok_of_slot, cnt, gate_value, out, 0, 0);
  } else {
    // per-expert fallback: h holds one expert's C rows (50 MB)
    for (int e=0; e<EEXP; e++){
      ffn_gemm<1><<<dim3(HDIM/128, CAP/128), 256, 0, stream>>>(
          x, W1, b1, tok_of_slot, cnt, gate_value, hbuf, e*(CAP/128), e*CAP);
      ffn_gemm<2><<<dim3(DDIM/128, CAP/128), 256, 0, stream>>>(
          hbuf, W2, b2, tok_of_slot, cnt, gate_value, out, e*(CAP/128), e*CAP);
    }
  }
  passthrough_kernel<<<NTOK, 256, 0, stream>>>(x, slot_or_neg, gate_value, out);
}

// Round 2
// 880.459 us; speedup vs baseline: 4.4521x; 4.4521x over previous
//
#include <hip/hip_runtime.h>

// Problem constants (B=8, S=2048, D=1024, H=4096, E=8, CAP_FACTOR=1.5)
#define NTOK 16384
#define DDIM 1024
#define EEXP 8
#define HDIM 4096
#define CAP  3072               // int(1.5 * 16384 / 8)
#define ECAP (EEXP*CAP)         // 24576
#define RT_PER_E (CAP/128)      // 24 row-tiles per expert

// Workspace layout (bytes)
#define OFF_GATE 0u                          // float[NTOK]
#define OFF_GIDX 65536u                      // int[NTOK]
#define OFF_SLOT 131072u                     // int[NTOK]
#define OFF_TOS  196608u                     // int[ECAP]
#define OFF_CNT  294912u                     // int[8]
#define OFF_PIMP 294976u                     // float[4096*8]
#define OFF_XBF  1048576u                    // ushort[NTOK*DDIM]       (32 MB)
#define OFF_W1T  34603008u                   // ushort[E*HDIM*DDIM]     (64 MB) [e][n][k]
#define OFF_W2T  101711872u                  // ushort[E*DDIM*HDIM]     (64 MB) [e][n][k]
#define OFF_HB   168820736u                  // ushort[ECAP*HDIM]       (192 MB)
#define WS_NEED  370147328u

typedef float f32x4  __attribute__((ext_vector_type(4)));
typedef short bf16x8 __attribute__((ext_vector_type(8)));

__device__ __forceinline__ unsigned short f2bf(float f){
  unsigned int u = __float_as_uint(f);
  unsigned int r = (u + 0x7fffu + ((u >> 16) & 1u)) >> 16;   // RNE
  return (unsigned short)r;
}
__device__ __forceinline__ float siluf(float v){ return v/(1.0f+__expf(-v)); }

// async global->LDS, 16B per lane; LDS dst must be wave-uniform base (+lane*16 implicit)
__device__ __forceinline__ void gl16(const void* g, void* l){
  __builtin_amdgcn_global_load_lds((const __attribute__((address_space(1))) unsigned int*)g,
                                   (__attribute__((address_space(3))) unsigned int*)l,
                                   16, 0, 0);
}

// ---------------------------------------------------------------------------
// Router: one wave per token. Also emits x in bf16 (fused conversion).
// ---------------------------------------------------------------------------
__global__ __launch_bounds__(256) void router_kernel(
    const float* __restrict__ x, const float* __restrict__ Wr,
    const float* __restrict__ br, float* __restrict__ gate_value,
    int* __restrict__ gate_idx, float* __restrict__ partial_imp,
    unsigned short* __restrict__ xbf)
{
  __shared__ float pbuf[4][8];
  const int wave = threadIdx.x >> 6;
  const int lane = threadIdx.x & 63;
  const int n = blockIdx.x*4 + wave;
  float acc[8];
#pragma unroll
  for (int e=0;e<8;e++) acc[e]=0.0f;
  const float* xr = x + (size_t)n*DDIM;
  unsigned short* xbr = xbf + (size_t)n*DDIM;
#pragma unroll
  for (int k=0;k<16;k++){
    const int d = k*64 + lane;
    const float xv = xr[d];
    xbr[d] = f2bf(xv);
    const float4 w0 = ((const float4*)(Wr + (size_t)d*8))[0];
    const float4 w1 = ((const float4*)(Wr + (size_t)d*8))[1];
    acc[0] += xv*w0.x; acc[1] += xv*w0.y; acc[2] += xv*w0.z; acc[3] += xv*w0.w;
    acc[4] += xv*w1.x; acc[5] += xv*w1.y; acc[6] += xv*w1.z; acc[7] += xv*w1.w;
  }
#pragma unroll
  for (int e=0;e<8;e++){
    acc[e] += __shfl_xor(acc[e], 32, 64);
    acc[e] += __shfl_xor(acc[e], 16, 64);
    acc[e] += __shfl_xor(acc[e],  8, 64);
    acc[e] += __shfl_xor(acc[e],  4, 64);
    acc[e] += __shfl_xor(acc[e],  2, 64);
    acc[e] += __shfl_xor(acc[e],  1, 64);
  }
  if (lane==0){
    float lg[8];
    float mx = -3.4e38f;
    int bi = 0;
#pragma unroll
    for (int e=0;e<8;e++) lg[e] = acc[e] + br[e];
#pragma unroll
    for (int e=0;e<8;e++){ if (lg[e] > mx){ mx = lg[e]; bi = e; } }
    float s = 0.f;
#pragma unroll
    for (int e=0;e<8;e++){ lg[e] = __expf(lg[e]-mx); s += lg[e]; }
    const float inv = 1.0f/s;
    gate_value[n] = inv;
    gate_idx[n] = bi;
#pragma unroll
    for (int e=0;e<8;e++) pbuf[wave][e] = lg[e]*inv;
  }
  __syncthreads();
  if (threadIdx.x < 8){
    partial_imp[(size_t)blockIdx.x*8 + threadIdx.x] =
      pbuf[0][threadIdx.x]+pbuf[1][threadIdx.x]+pbuf[2][threadIdx.x]+pbuf[3][threadIdx.x];
  }
}

// ---------------------------------------------------------------------------
// Scan: FIFO positions per expert (single block) + aux losses.
// ---------------------------------------------------------------------------
__global__ __launch_bounds__(256) void scan_kernel(
    const int* __restrict__ gate_idx, const float* __restrict__ partial_imp,
    int* __restrict__ slot_or_neg, int* __restrict__ tok_of_slot,
    int* __restrict__ cnt, float* __restrict__ out_losses)
{
  __shared__ int hist[256][8];
  __shared__ float impbuf[32][8];
  const int t = threadIdx.x;
  int h[8];
#pragma unroll
  for (int e=0;e<8;e++) h[e]=0;
  const int base = t*64;
  for (int i=0;i<64;i++) h[gate_idx[base+i]]++;
#pragma unroll
  for (int e=0;e<8;e++) hist[t][e]=h[e];
  {
    const int e = t & 7, c = t >> 3;
    float s = 0.f;
    for (int r=c; r<4096; r+=32) s += partial_imp[(size_t)r*8+e];
    impbuf[c][e] = s;
  }
  __syncthreads();
  if (t < 8){
    int run = 0;
    for (int i=0;i<256;i++){ int v = hist[i][t]; hist[i][t] = run; run += v; }
    cnt[t] = run < CAP ? run : CAP;
  }
  __syncthreads();
#pragma unroll
  for (int e=0;e<8;e++) h[e]=hist[t][e];
  for (int i=0;i<64;i++){
    const int n = base+i;
    const int e = gate_idx[n];
    const int p = h[e]++;
    if (p < CAP){ const int s = e*CAP+p; slot_or_neg[n]=s; tok_of_slot[s]=n; }
    else slot_or_neg[n] = -1;
  }
  if (t==0){
    float imp[8]; float m = 0.f;
    for (int e=0;e<8;e++){ float s=0.f; for (int c=0;c<32;c++) s+=impbuf[c][e]; imp[e]=s; m+=s; }
    m *= 0.125f;
    float var = 0.f;
    for (int e=0;e<8;e++){ const float d=imp[e]-m; var += d*d; }
    var *= 0.125f;
    out_losses[0] = 1.0f;
    out_losses[1] = var/(m*m);
  }
}

// ---------------------------------------------------------------------------
// Weight transpose + fp32->bf16: W [E][K][N] -> Wt [E][N][K] (k-contiguous rows,
// as required by the MFMA B-operand). grid (N/32, K/32, E), 256 threads.
// ---------------------------------------------------------------------------
__global__ __launch_bounds__(256) void cvt_w_t(
    const float* __restrict__ W, unsigned short* __restrict__ Wt, int K, int N)
{
  __shared__ float t[32][33];
  const int e = blockIdx.z;
  const int n0 = blockIdx.x*32, k0 = blockIdx.y*32;
  const int r = threadIdx.x>>3, c4 = (threadIdx.x&7)*4;
  const float4 v = *(const float4*)(W + ((size_t)e*K + k0 + r)*N + n0 + c4);
  t[r][c4+0]=v.x; t[r][c4+1]=v.y; t[r][c4+2]=v.z; t[r][c4+3]=v.w;
  __syncthreads();
  ushort4 o;
  o.x = f2bf(t[c4+0][r]); o.y = f2bf(t[c4+1][r]);
  o.z = f2bf(t[c4+2][r]); o.w = f2bf(t[c4+3][r]);
  *(ushort4*)(Wt + ((size_t)e*N + n0 + r)*K + k0 + c4) = o;
}

// ---------------------------------------------------------------------------
// MFMA grouped FFN GEMM (m97 structure): 128x128 tile, BK=32 bf16, 4 waves,
// each wave 64x64 via 4x4 grid of v_mfma_f32_16x16x32_bf16.
// LDS: As/Bs 128 rows x 32 bf16, 16B chunks XOR-swizzled: chunk(r,kg) at
// r*64 + (kg ^ ((r>>1)&3))*16  -> ds_read_b128 fragment reads are 2-way only.
// Staged via global_load_lds width 16 (per-lane global gather is allowed;
// LDS side is wave-uniform base + lane*16).
// PHASE 1: hbf = bf16(silu(Xg @ W1^T' + b1));  PHASE 2: out[tok] = (h @ W2^T' + b2)*gate
// ---------------------------------------------------------------------------
template<int PHASE>
__global__ __launch_bounds__(256) void ffn_mfma(
    const unsigned short* __restrict__ A,   // PHASE1: xbf [NTOK][1024]; PHASE2: hbf [ECAP][4096]
    const unsigned short* __restrict__ Bt,  // [E][NN][K] k-contiguous
    const float* __restrict__ bias,         // [E][NN]
    const int* __restrict__ tok_of_slot,
    const int* __restrict__ cnt,
    const float* __restrict__ gate_value,
    void* __restrict__ Out)
{
  constexpr int K  = (PHASE==1)? DDIM : HDIM;
  constexpr int NN = (PHASE==1)? HDIM : DDIM;
  const int rowtile = blockIdx.y;
  const int coltile = blockIdx.x;
  const int e  = rowtile / RT_PER_E;
  const int r0 = (rowtile - e*RT_PER_E)*128;
  const int ce = cnt[e];
  if (r0 >= ce) return;                     // block-uniform early exit

  __shared__ alignas(16) char smem[16384];
  char* As  = smem;
  char* Bsm = smem + 8192;

  const int tid  = threadIdx.x;
  const int l    = tid & 63;
  const int wv   = __builtin_amdgcn_readfirstlane(tid >> 6);

  // ---- staging addresses (2 A chunks + 2 B chunks per lane per K-step)
  const int sub = l >> 2;                   // 0..15
  const int c   = l & 3;
  const int gr0 = wv*16 + sub;              // tile rows 0..63
  const int gr1 = 64 + gr0;                 // tile rows 64..127
  const int kg0 = c ^ ((gr0>>1)&3);
  const int kg1 = c ^ ((gr1>>1)&3);

  const unsigned short *agp0, *agp1;
  if (PHASE==1){
    const int t0 = (r0 + gr0 < ce) ? tok_of_slot[rowtile*128 + gr0] : 0;
    const int t1 = (r0 + gr1 < ce) ? tok_of_slot[rowtile*128 + gr1] : 0;
    agp0 = A + (size_t)t0*K + kg0*8;
    agp1 = A + (size_t)t1*K + kg1*8;
  } else {
    agp0 = A + (size_t)(rowtile*128 + gr0)*K + kg0*8;
    agp1 = A + (size_t)(rowtile*128 + gr1)*K + kg1*8;
  }
  const unsigned short* bgp0 = Bt + ((size_t)e*NN + coltile*128 + gr0)*K + kg0*8;
  const unsigned short* bgp1 = Bt + ((size_t)e*NN + coltile*128 + gr1)*K + kg1*8;

  char* a_dst0 = As  + wv*1024;  char* a_dst1 = As  + 4096 + wv*1024;
  char* b_dst0 = Bsm + wv*1024;  char* b_dst1 = Bsm + 4096 + wv*1024;

  // ---- fragment read offsets
  const int wrow = (wv & 1)*64, wcol = (wv >> 1)*64;
  const int lm  = l & 15;
  const int kgf = l >> 4;                   // 0..3
  int aoff[4], boff[4];
#pragma unroll
  for (int i=0;i<4;i++){
    const int ra = wrow + i*16 + lm;
    aoff[i] = ra*64 + ((kgf ^ ((ra>>1)&3))*16);
    const int rb = wcol + i*16 + lm;
    boff[i] = rb*64 + ((kgf ^ ((rb>>1)&3))*16);
  }

  f32x4 acc[4][4];
#pragma unroll
  for (int i=0;i<4;i++)
#pragma unroll
    for (int j=0;j<4;j++) acc[i][j] = (f32x4){0.f,0.f,0.f,0.f};

  for (int k0 = 0; k0 < K; k0 += 32){
    __syncthreads();                        // prev iter done reading LDS
    gl16(agp0 + k0, a_dst0);
    gl16(agp1 + k0, a_dst1);
    gl16(bgp0 + k0, b_dst0);
    gl16(bgp1 + k0, b_dst1);
    __syncthreads();                        // drains vmcnt -> staging visible
    bf16x8 af[4], bf[4];
#pragma unroll
    for (int i=0;i<4;i++) af[i] = *(const bf16x8*)(As  + aoff[i]);
#pragma unroll
    for (int i=0;i<4;i++) bf[i] = *(const bf16x8*)(Bsm + boff[i]);
#pragma unroll
    for (int mi=0;mi<4;mi++)
#pragma unroll
      for (int ni=0;ni<4;ni++)
        acc[mi][ni] = __builtin_amdgcn_mfma_f32_16x16x32_bf16(af[mi], bf[ni], acc[mi][ni], 0, 0, 0);
  }

  // ---- epilogue. C/D layout: col = lane&15, row = (lane>>4)*4 + reg
  const float* bp = bias + (size_t)e*NN + coltile*128 + wcol;
  float bv[4];
#pragma unroll
  for (int ni=0;ni<4;ni++) bv[ni] = bp[ni*16 + lm];

  if (PHASE==1){
    unsigned short* hb = (unsigned short*)Out;
#pragma unroll
    for (int mi=0;mi<4;mi++){
#pragma unroll
      for (int r=0;r<4;r++){
        const int row = wrow + mi*16 + kgf*4 + r;
        unsigned short* hr = hb + (size_t)(rowtile*128 + row)*NN + coltile*128 + wcol;
#pragma unroll
        for (int ni=0;ni<4;ni++){
          const float v = acc[mi][ni][r] + bv[ni];
          hr[ni*16 + lm] = f2bf(siluf(v));
        }
      }
    }
  } else {
    float* op = (float*)Out;
#pragma unroll
    for (int mi=0;mi<4;mi++){
#pragma unroll
      for (int r=0;r<4;r++){
        const int row = wrow + mi*16 + kgf*4 + r;
        if (r0 + row < ce){
          const int tok = tok_of_slot[rowtile*128 + row];
          const float g = gate_value[tok];
          float* orow = op + (size_t)tok*NN + coltile*128 + wcol;
#pragma unroll
          for (int ni=0;ni<4;ni++)
            orow[ni*16 + lm] = (acc[mi][ni][r] + bv[ni])*g;
        }
      }
    }
  }
}

// ---------------------------------------------------------------------------
// Dropped tokens pass through: out[n] = x[n] * gate[n]
// ---------------------------------------------------------------------------
__global__ __launch_bounds__(256) void passthrough_kernel(
    const float* __restrict__ x, const int* __restrict__ slot_or_neg,
    const float* __restrict__ gate_value, float* __restrict__ out)
{
  const int n = blockIdx.x;
  if (slot_or_neg[n] >= 0) return;
  const float g = gate_value[n];
  float4 v = *(const float4*)(x + (size_t)n*DDIM + threadIdx.x*4);
  v.x*=g; v.y*=g; v.z*=g; v.w*=g;
  *(float4*)(out + (size_t)n*DDIM + threadIdx.x*4) = v;
}

extern "C" void kernel_launch(void* const* d_in, const int* in_sizes, int n_in,
                              void* d_out, int out_size, void* d_ws, size_t ws_size,
                              hipStream_t stream)
{
  const float* x  = (const float*)d_in[0];
  const float* Wr = (const float*)d_in[1];
  const float* br = (const float*)d_in[2];
  const float* W1 = (const float*)d_in[3];
  const float* b1 = (const float*)d_in[4];
  const float* W2 = (const float*)d_in[5];
  const float* b2 = (const float*)d_in[6];
  float* out = (float*)d_out;

  char* ws = (char*)d_ws;
  float*          gate_value  = (float*)(ws + OFF_GATE);
  int*            gate_idx    = (int*)  (ws + OFF_GIDX);
  int*            slot_or_neg = (int*)  (ws + OFF_SLOT);
  int*            tok_of_slot = (int*)  (ws + OFF_TOS);
  int*            cnt         = (int*)  (ws + OFF_CNT);
  float*          partial_imp = (float*)(ws + OFF_PIMP);
  unsigned short* xbf         = (unsigned short*)(ws + OFF_XBF);
  unsigned short* W1t         = (unsigned short*)(ws + OFF_W1T);
  unsigned short* W2t         = (unsigned short*)(ws + OFF_W2T);
  unsigned short* hbf         = (unsigned short*)(ws + OFF_HB);

  // weight transpose+convert (independent of router/scan)
  cvt_w_t<<<dim3(HDIM/32, DDIM/32, EEXP), 256, 0, stream>>>(W1, W1t, DDIM, HDIM);
  cvt_w_t<<<dim3(DDIM/32, HDIM/32, EEXP), 256, 0, stream>>>(W2, W2t, HDIM, DDIM);

  router_kernel<<<NTOK/4, 256, 0, stream>>>(x, Wr, br, gate_value, gate_idx,
                                            partial_imp, xbf);
  scan_kernel<<<1, 256, 0, stream>>>(gate_idx, partial_imp, slot_or_neg, tok_of_slot,
                                     cnt, out + (size_t)NTOK*DDIM);

  ffn_mfma<1><<<dim3(HDIM/128, ECAP/128), 256, 0, stream>>>(
      xbf, W1t, b1, tok_of_slot, cnt, gate_value, (void*)hbf);
  ffn_mfma<2><<<dim3(DDIM/128, ECAP/128), 256, 0, stream>>>(
      hbf, W2t, b2, tok_of_slot, cnt, gate_value, (void*)out);

  passthrough_kernel<<<NTOK, 256, 0, stream>>>(x, slot_or_neg, gate_value, out);
}